// Round 1
// baseline (472.900 us; speedup 1.0000x reference)
//
#include <hip/hip_runtime.h>

// Fused: LN-free MHA block  out = LayerNorm(x + MHA(x))
// B=4, S=2048, D=1024, H=16, dk=64.
// Internal compute bf16 MFMA (threshold 1.1e-1 permits), fp32 I/O.
//
// ws layout (bytes), total 75,497,472 (~72 MB):
//   x_bf    [8192*1024] u16   (aliased by ctx_bf after QKV GEMM consumes x_bf)
//   Wqkv_bf [3072*1024] u16   (Wq rows 0-1023, Wk 1024-2047, Wv 2048-3071)
//   Wo_bf   [1024*1024] u16
//   Q_bf    [64*2048*64] u16  (B,H,S,dk), pre-scaled by 1/sqrt(dk)
//   K_bf    [64*2048*64] u16  (B,H,S,dk)
//   Vt_bf   [64*64*2048] u16  (B,H,dk,S)  transposed for MFMA PV B-operand

#define SEQ 2048
#define DMODEL 1024
#define NH 16
#define DK 64
#define NROWS 8192  // B*S

typedef unsigned short u16;
typedef __bf16 bf16;
typedef bf16 bf16x8 __attribute__((ext_vector_type(8)));
typedef float f32x4 __attribute__((ext_vector_type(4)));

__device__ inline u16 f2bf(float f) {
    union { float f; unsigned u; } v; v.f = f;
    unsigned u = v.u;
    u += 0x7FFFu + ((u >> 16) & 1u);   // RNE (inputs finite)
    return (u16)(u >> 16);
}

// ---------------- fp32 -> bf16 convert ----------------
__global__ __launch_bounds__(256) void cvt_f32_bf16(const float* __restrict__ in,
                                                    u16* __restrict__ out, int n) {
    int i = (blockIdx.x * 256 + threadIdx.x) * 4;
    if (i >= n) return;
    float4 v = *(const float4*)(in + i);
    ushort4 o;
    o.x = f2bf(v.x); o.y = f2bf(v.y); o.z = f2bf(v.z); o.w = f2bf(v.w);
    *(ushort4*)(out + i) = o;
}

// ---------------- GEMM: C[M,N] = A[M,K] @ W[N,K]^T (+epilogue) ----------------
// 128x128 tile, BK=32, 256 threads = 4 waves (2x2), each wave 64x64 = 4x4 frags.
// EPI 0: QKV scatter (N=3072), EPI 1: O-proj + bias + residual -> fp32 y
template <int EPI>
__global__ __launch_bounds__(256) void gemm_bt(
    const u16* __restrict__ A, const u16* __restrict__ Bm, int K,
    const float* __restrict__ bias0, const float* __restrict__ bias1,
    const float* __restrict__ bias2,
    u16* __restrict__ Qo, u16* __restrict__ Ko, u16* __restrict__ Vo,
    const float* __restrict__ xres, float* __restrict__ yout) {
    __shared__ __align__(16) u16 As[128 * 32];
    __shared__ __align__(16) u16 Bs[128 * 32];

    const int tid  = threadIdx.x;
    const int lane = tid & 63;
    const int w    = tid >> 6;
    const int wr   = (w >> 1) * 64;
    const int wc   = (w & 1) * 64;
    const int l16  = lane & 15;
    const int lk   = (lane >> 4) * 8;
    const int m0   = blockIdx.x * 128;
    const int n0   = blockIdx.y * 128;

    f32x4 acc[4][4];
#pragma unroll
    for (int m = 0; m < 4; m++)
#pragma unroll
        for (int n = 0; n < 4; n++) {
            f32x4 z = {0.f, 0.f, 0.f, 0.f};
            acc[m][n] = z;
        }

    // staging: per thread 2x16B of A-tile, 2x16B of B-tile
    const int srow = tid >> 2;          // 0..63
    const int scol = (tid & 3) * 8;     // elem col
    const u16* Ag0 = A + (size_t)(m0 + srow) * K + scol;
    const u16* Ag1 = Ag0 + (size_t)64 * K;
    const u16* Bg0 = Bm + (size_t)(n0 + srow) * K + scol;
    const u16* Bg1 = Bg0 + (size_t)64 * K;

    for (int k0 = 0; k0 < K; k0 += 32) {
        uint4 a0 = *(const uint4*)(Ag0 + k0);
        uint4 a1 = *(const uint4*)(Ag1 + k0);
        uint4 b0 = *(const uint4*)(Bg0 + k0);
        uint4 b1 = *(const uint4*)(Bg1 + k0);
        __syncthreads();   // previous iteration's LDS reads done
        *(uint4*)&As[srow * 32 + scol]        = a0;
        *(uint4*)&As[(srow + 64) * 32 + scol] = a1;
        *(uint4*)&Bs[srow * 32 + scol]        = b0;
        *(uint4*)&Bs[(srow + 64) * 32 + scol] = b1;
        __syncthreads();

        bf16x8 af[4], bfr[4];
#pragma unroll
        for (int m = 0; m < 4; m++)
            af[m] = *(const bf16x8*)&As[(wr + m * 16 + l16) * 32 + lk];
#pragma unroll
        for (int n = 0; n < 4; n++)
            bfr[n] = *(const bf16x8*)&Bs[(wc + n * 16 + l16) * 32 + lk];
#pragma unroll
        for (int m = 0; m < 4; m++)
#pragma unroll
            for (int n = 0; n < 4; n++)
                acc[m][n] = __builtin_amdgcn_mfma_f32_16x16x32_bf16(
                    af[m], bfr[n], acc[m][n], 0, 0, 0);
    }

    // epilogue. D-frag: col = lane&15, row = (lane>>4)*4 + r  [m89 verified]
    const int rbase = m0 + wr + (lane >> 4) * 4;
    const int cbase = n0 + wc + l16;
#pragma unroll
    for (int m = 0; m < 4; m++)
#pragma unroll
        for (int n = 0; n < 4; n++) {
            const int col = cbase + n * 16;
#pragma unroll
            for (int r = 0; r < 4; r++) {
                const int row = rbase + m * 16 + r;
                float v = acc[m][n][r];
                if (EPI == 0) {
                    const int which = col >> 10;
                    const int e = col & 1023;
                    const float* bs = (which == 0) ? bias0 : (which == 1) ? bias1 : bias2;
                    v += bs[e];
                    if (which == 0) v *= 0.125f;  // fold 1/sqrt(dk) into Q
                    const int h = e >> 6, d = e & 63;
                    const int b = row >> 11, s = row & 2047;
                    const int bh = b * NH + h;
                    if (which == 2)
                        Vo[((size_t)bh * DK + d) * SEQ + s] = f2bf(v);
                    else if (which == 0)
                        Qo[((size_t)bh * SEQ + s) * DK + d] = f2bf(v);
                    else
                        Ko[((size_t)bh * SEQ + s) * DK + d] = f2bf(v);
                } else {
                    v += bias0[col] + xres[(size_t)row * DMODEL + col];
                    yout[(size_t)row * DMODEL + col] = v;
                }
            }
        }
}

// ---------------- flash attention ----------------
// grid (S/64, B*H). 4 waves/block, wave w owns q rows [q0+16w, q0+16w+16).
// K-tile = 32 kpos staged in LDS (shared), V^T staged in LDS.
__global__ __launch_bounds__(256) void attn(const u16* __restrict__ Qb,
                                            const u16* __restrict__ Kb,
                                            const u16* __restrict__ Vtb,
                                            u16* __restrict__ ctx) {
    __shared__ __align__(16) u16 Kl[32 * 64];      // [kpos][d]
    __shared__ __align__(16) u16 Vl[64 * 32];      // [d][kpos]
    __shared__ __align__(16) u16 Pl[4 * 16 * 32];  // per wave [qrow][kpos]

    const int tid  = threadIdx.x;
    const int lane = tid & 63;
    const int w    = tid >> 6;
    const int l16  = lane & 15;
    const int g    = lane >> 4;
    const int bh   = blockIdx.y;
    const int q0   = blockIdx.x * 64 + w * 16;

    // Q fragments (A-operand, rows = q, kdim = d). Q pre-scaled by 1/8.
    const u16* qptr = Qb + ((size_t)bh * SEQ + q0 + l16) * DK + g * 8;
    bf16x8 qf0 = *(const bf16x8*)qptr;
    bf16x8 qf1 = *(const bf16x8*)(qptr + 32);

    float m_[4], l_[4];
    f32x4 oacc[4];
#pragma unroll
    for (int r = 0; r < 4; r++) { m_[r] = -1e30f; l_[r] = 0.f; }
#pragma unroll
    for (int dn = 0; dn < 4; dn++) {
        f32x4 z = {0.f, 0.f, 0.f, 0.f};
        oacc[dn] = z;
    }

    const u16* Kg = Kb + ((size_t)bh * SEQ + (tid >> 3)) * DK + (tid & 7) * 8;
    const u16* Vg = Vtb + ((size_t)bh * DK + (tid >> 2)) * SEQ + (tid & 3) * 8;

    for (int k0 = 0; k0 < SEQ; k0 += 32) {
        uint4 kv = *(const uint4*)(Kg + (size_t)k0 * DK);
        uint4 vv = *(const uint4*)(Vg + k0);
        __syncthreads();
        *(uint4*)&Kl[(tid >> 3) * 64 + (tid & 7) * 8] = kv;
        *(uint4*)&Vl[(tid >> 2) * 32 + (tid & 3) * 8] = vv;
        __syncthreads();

        // S^tile = Q K^T : two 16-col fragments
        f32x4 s[2];
#pragma unroll
        for (int kt = 0; kt < 2; kt++) {
            bf16x8 kf0 = *(const bf16x8*)&Kl[(kt * 16 + l16) * 64 + g * 8];
            bf16x8 kf1 = *(const bf16x8*)&Kl[(kt * 16 + l16) * 64 + 32 + g * 8];
            f32x4 z = {0.f, 0.f, 0.f, 0.f};
            z = __builtin_amdgcn_mfma_f32_16x16x32_bf16(qf0, kf0, z, 0, 0, 0);
            z = __builtin_amdgcn_mfma_f32_16x16x32_bf16(qf1, kf1, z, 0, 0, 0);
            s[kt] = z;
        }

        // online softmax (rows of S-frag: row = g*4+r, col = kpos = kt*16+l16)
#pragma unroll
        for (int r = 0; r < 4; r++) {
            float s0 = s[0][r], s1 = s[1][r];
            float mx = fmaxf(s0, s1);
            mx = fmaxf(mx, __shfl_xor(mx, 1));
            mx = fmaxf(mx, __shfl_xor(mx, 2));
            mx = fmaxf(mx, __shfl_xor(mx, 4));
            mx = fmaxf(mx, __shfl_xor(mx, 8));
            float mnew = fmaxf(m_[r], mx);
            float sc = __expf(m_[r] - mnew);
            float p0 = __expf(s0 - mnew);
            float p1 = __expf(s1 - mnew);
            float ps = p0 + p1;
            ps += __shfl_xor(ps, 1);
            ps += __shfl_xor(ps, 2);
            ps += __shfl_xor(ps, 4);
            ps += __shfl_xor(ps, 8);
            l_[r] = l_[r] * sc + ps;
            m_[r] = mnew;
#pragma unroll
            for (int dn = 0; dn < 4; dn++) oacc[dn][r] *= sc;
            const int qrow = g * 4 + r;
            Pl[w * 512 + qrow * 32 + l16]      = f2bf(p0);
            Pl[w * 512 + qrow * 32 + 16 + l16] = f2bf(p1);
        }

        // PV: A = P (rows=q, k=kpos), B = V^T (col=d, k=kpos)
        bf16x8 pa = *(const bf16x8*)&Pl[w * 512 + l16 * 32 + g * 8];
#pragma unroll
        for (int dn = 0; dn < 4; dn++) {
            bf16x8 vb = *(const bf16x8*)&Vl[(dn * 16 + l16) * 32 + g * 8];
            oacc[dn] = __builtin_amdgcn_mfma_f32_16x16x32_bf16(pa, vb, oacc[dn], 0, 0, 0);
        }
    }

    // write ctx (B,S,D) bf16
    const int b = bh >> 4, h = bh & 15;
#pragma unroll
    for (int dn = 0; dn < 4; dn++)
#pragma unroll
        for (int r = 0; r < 4; r++) {
            const int qrow = q0 + g * 4 + r;
            float v = oacc[dn][r] / l_[r];
            ctx[((size_t)(b * SEQ + qrow)) * DMODEL + h * DK + dn * 16 + l16] = f2bf(v);
        }
}

// ---------------- in-place LayerNorm over rows of y ----------------
__global__ __launch_bounds__(256) void ln_inplace(float* __restrict__ y,
                                                  const float* __restrict__ gamma,
                                                  const float* __restrict__ beta) {
    const int row = blockIdx.x;
    float* p = y + (size_t)row * DMODEL;
    const int tid = threadIdx.x;
    float4 v = *(const float4*)(p + tid * 4);
    float s  = v.x + v.y + v.z + v.w;
    float sq = v.x * v.x + v.y * v.y + v.z * v.z + v.w * v.w;
#pragma unroll
    for (int m = 1; m < 64; m <<= 1) {
        s  += __shfl_xor(s, m);
        sq += __shfl_xor(sq, m);
    }
    __shared__ float rs[4], rq[4];
    if ((tid & 63) == 0) { rs[tid >> 6] = s; rq[tid >> 6] = sq; }
    __syncthreads();
    s  = rs[0] + rs[1] + rs[2] + rs[3];
    sq = rq[0] + rq[1] + rq[2] + rq[3];
    const float mean = s * (1.0f / 1024.0f);
    const float var  = sq * (1.0f / 1024.0f) - mean * mean;
    const float inv  = rsqrtf(var + 1e-5f);
    const int c = tid * 4;
    float4 g4 = *(const float4*)(gamma + c);
    float4 b4 = *(const float4*)(beta + c);
    float4 o;
    o.x = (v.x - mean) * inv * g4.x + b4.x;
    o.y = (v.y - mean) * inv * g4.y + b4.y;
    o.z = (v.z - mean) * inv * g4.z + b4.z;
    o.w = (v.w - mean) * inv * g4.w + b4.w;
    *(float4*)(p + c) = o;
}

extern "C" void kernel_launch(void* const* d_in, const int* in_sizes, int n_in,
                              void* d_out, int out_size, void* d_ws, size_t ws_size,
                              hipStream_t stream) {
    const float* x     = (const float*)d_in[0];
    const float* Wq    = (const float*)d_in[1];
    const float* bq    = (const float*)d_in[2];
    const float* Wk    = (const float*)d_in[3];
    const float* bk    = (const float*)d_in[4];
    const float* Wv    = (const float*)d_in[5];
    const float* bv    = (const float*)d_in[6];
    const float* Wo    = (const float*)d_in[7];
    const float* bo    = (const float*)d_in[8];
    const float* gamma = (const float*)d_in[9];
    const float* beta  = (const float*)d_in[10];
    float* out = (float*)d_out;

    u16* x_bf    = (u16*)d_ws;
    u16* Wqkv_bf = x_bf + (size_t)NROWS * DMODEL;           // +8388608
    u16* Wo_bf   = Wqkv_bf + (size_t)3072 * 1024;           // +3145728
    u16* Q_bf    = Wo_bf + (size_t)1024 * 1024;             // +1048576
    u16* K_bf    = Q_bf + (size_t)64 * SEQ * DK;            // +8388608
    u16* Vt_bf   = K_bf + (size_t)64 * SEQ * DK;
    u16* ctx_bf  = x_bf;  // alias: x_bf dead after QKV GEMM

    cvt_f32_bf16<<<8192, 256, 0, stream>>>(x, x_bf, NROWS * DMODEL);
    cvt_f32_bf16<<<1024, 256, 0, stream>>>(Wq, Wqkv_bf, 1024 * 1024);
    cvt_f32_bf16<<<1024, 256, 0, stream>>>(Wk, Wqkv_bf + 1048576, 1024 * 1024);
    cvt_f32_bf16<<<1024, 256, 0, stream>>>(Wv, Wqkv_bf + 2097152, 1024 * 1024);
    cvt_f32_bf16<<<1024, 256, 0, stream>>>(Wo, Wo_bf, 1024 * 1024);

    gemm_bt<0><<<dim3(64, 24), 256, 0, stream>>>(x_bf, Wqkv_bf, 1024,
                                                 bq, bk, bv, Q_bf, K_bf, Vt_bf,
                                                 nullptr, nullptr);
    attn<<<dim3(32, 64), 256, 0, stream>>>(Q_bf, K_bf, Vt_bf, ctx_bf);
    gemm_bt<1><<<dim3(64, 8), 256, 0, stream>>>(ctx_bf, Wo_bf, 1024,
                                                bo, nullptr, nullptr,
                                                nullptr, nullptr, nullptr,
                                                x, out);
    ln_inplace<<<8192, 256, 0, stream>>>(out, gamma, beta);
}

// Round 2
// 260.147 us; speedup vs baseline: 1.8178x; 1.8178x over previous
//
#include <hip/hip_runtime.h>

// Fused MHA block: out = LayerNorm(x + MHA(x)).  B=4, S=2048, D=1024, H=16, dk=64.
// bf16 MFMA internal, fp32 I/O.
//
// Round 2: attn rewritten to swapped-QK^T 32x32 MFMA structure (m214 recipe):
//  - mfma(K,Q) -> S^T: lane holds 16/32 kpos for one q-row -> in-register softmax
//    (15 fmax + 1 shfl_xor(32)), exp2 with log2e folded into Q pre-scale.
//  - P packed to bf16 in-register, 8x shfl_xor(32) exchange -> PV B-operand.
//  - PV as O^T = V^T * P^T (rescale factor lane-uniform).
//  - K_lds XOR-swizzled (16-way -> 4-way), Vt_lds padded rows (40 elems).
//  - 8 waves x 32 q-rows = 256 q/block; KVBLK=32, double-buffered LDS.
//  - defer-max (THR=8 in log2 domain); ctx written via swizzled LDS bounce.

#define SEQ 2048
#define DMODEL 1024
#define NH 16
#define DK 64
#define NROWS 8192  // B*S

typedef unsigned short u16;
typedef unsigned int u32;
typedef __bf16 bf16;
typedef bf16 bf16x8 __attribute__((ext_vector_type(8)));
typedef float f32x4 __attribute__((ext_vector_type(4)));
typedef float f32x16 __attribute__((ext_vector_type(16)));

#if __has_builtin(__builtin_amdgcn_exp2f)
#define EXP2(x) __builtin_amdgcn_exp2f(x)
#else
#define EXP2(x) __expf((x)*0.6931471805599453f)
#endif

__device__ inline u16 f2bf(float f) {
    union { float f; unsigned u; } v; v.f = f;
    unsigned u = v.u;
    u += 0x7FFFu + ((u >> 16) & 1u);   // RNE (finite inputs)
    return (u16)(u >> 16);
}
__device__ inline u32 pack2bf(float lo, float hi_) {
    return (u32)f2bf(lo) | ((u32)f2bf(hi_) << 16);
}

// ---------------- fp32 -> bf16 convert ----------------
__global__ __launch_bounds__(256) void cvt_f32_bf16(const float* __restrict__ in,
                                                    u16* __restrict__ out, int n) {
    int i = (blockIdx.x * 256 + threadIdx.x) * 4;
    if (i >= n) return;
    float4 v = *(const float4*)(in + i);
    ushort4 o;
    o.x = f2bf(v.x); o.y = f2bf(v.y); o.z = f2bf(v.z); o.w = f2bf(v.w);
    *(ushort4*)(out + i) = o;
}

// ---------------- GEMM: C[M,N] = A[M,K] @ W[N,K]^T (+epilogue) ----------------
template <int EPI>
__global__ __launch_bounds__(256) void gemm_bt(
    const u16* __restrict__ A, const u16* __restrict__ Bm, int K,
    const float* __restrict__ bias0, const float* __restrict__ bias1,
    const float* __restrict__ bias2,
    u16* __restrict__ Qo, u16* __restrict__ Ko, u16* __restrict__ Vo,
    const float* __restrict__ xres, float* __restrict__ yout) {
    __shared__ __align__(16) u16 As[128 * 32];
    __shared__ __align__(16) u16 Bs[128 * 32];

    const int tid  = threadIdx.x;
    const int lane = tid & 63;
    const int w    = tid >> 6;
    const int wr   = (w >> 1) * 64;
    const int wc   = (w & 1) * 64;
    const int l16  = lane & 15;
    const int lk   = (lane >> 4) * 8;
    const int m0   = blockIdx.x * 128;
    const int n0   = blockIdx.y * 128;

    f32x4 acc[4][4];
#pragma unroll
    for (int m = 0; m < 4; m++)
#pragma unroll
        for (int n = 0; n < 4; n++) {
            f32x4 z = {0.f, 0.f, 0.f, 0.f};
            acc[m][n] = z;
        }

    const int srow = tid >> 2;
    const int scol = (tid & 3) * 8;
    const u16* Ag0 = A + (size_t)(m0 + srow) * K + scol;
    const u16* Ag1 = Ag0 + (size_t)64 * K;
    const u16* Bg0 = Bm + (size_t)(n0 + srow) * K + scol;
    const u16* Bg1 = Bg0 + (size_t)64 * K;

    for (int k0 = 0; k0 < K; k0 += 32) {
        uint4 a0 = *(const uint4*)(Ag0 + k0);
        uint4 a1 = *(const uint4*)(Ag1 + k0);
        uint4 b0 = *(const uint4*)(Bg0 + k0);
        uint4 b1 = *(const uint4*)(Bg1 + k0);
        __syncthreads();
        *(uint4*)&As[srow * 32 + scol]        = a0;
        *(uint4*)&As[(srow + 64) * 32 + scol] = a1;
        *(uint4*)&Bs[srow * 32 + scol]        = b0;
        *(uint4*)&Bs[(srow + 64) * 32 + scol] = b1;
        __syncthreads();

        bf16x8 af[4], bfr[4];
#pragma unroll
        for (int m = 0; m < 4; m++)
            af[m] = *(const bf16x8*)&As[(wr + m * 16 + l16) * 32 + lk];
#pragma unroll
        for (int n = 0; n < 4; n++)
            bfr[n] = *(const bf16x8*)&Bs[(wc + n * 16 + l16) * 32 + lk];
#pragma unroll
        for (int m = 0; m < 4; m++)
#pragma unroll
            for (int n = 0; n < 4; n++)
                acc[m][n] = __builtin_amdgcn_mfma_f32_16x16x32_bf16(
                    af[m], bfr[n], acc[m][n], 0, 0, 0);
    }

    const int rbase = m0 + wr + (lane >> 4) * 4;
    const int cbase = n0 + wc + l16;
#pragma unroll
    for (int m = 0; m < 4; m++)
#pragma unroll
        for (int n = 0; n < 4; n++) {
            const int col = cbase + n * 16;
#pragma unroll
            for (int r = 0; r < 4; r++) {
                const int row = rbase + m * 16 + r;
                float v = acc[m][n][r];
                if (EPI == 0) {
                    const int which = col >> 10;
                    const int e = col & 1023;
                    const float* bs = (which == 0) ? bias0 : (which == 1) ? bias1 : bias2;
                    v += bs[e];
                    // fold 1/sqrt(dk) * log2(e) into Q (softmax done in exp2 domain)
                    if (which == 0) v *= 0.18033688011112042f;
                    const int h = e >> 6, d = e & 63;
                    const int b = row >> 11, s = row & 2047;
                    const int bh = b * NH + h;
                    if (which == 2)
                        Vo[((size_t)bh * DK + d) * SEQ + s] = f2bf(v);
                    else if (which == 0)
                        Qo[((size_t)bh * SEQ + s) * DK + d] = f2bf(v);
                    else
                        Ko[((size_t)bh * SEQ + s) * DK + d] = f2bf(v);
                } else {
                    v += bias0[col] + xres[(size_t)row * DMODEL + col];
                    yout[(size_t)row * DMODEL + col] = v;
                }
            }
        }
}

// ---------------- flash attention, swapped-QK^T 32x32 structure ----------------
// grid (S/256, B*H), 512 threads = 8 waves; wave w owns q rows [q0, q0+32).
// Per k-tile of 32: S^T = K.Q^T (4 mfma), in-register softmax, O^T += V^T.P^T (4 mfma).
__global__ __launch_bounds__(512) void attn(const u16* __restrict__ Qb,
                                            const u16* __restrict__ Kb,
                                            const u16* __restrict__ Vtb,
                                            u16* __restrict__ ctx) {
    // smem carve: K tiles 2x[32][64] at 0..4095, V^T tiles 2x[64][40] at 4096..9215;
    // whole 16384 reused as per-wave output bounce (8 waves x 2048 elems).
    __shared__ __align__(16) u16 smem[16384];

    const int tid  = threadIdx.x;
    const int lane = tid & 63;
    const int w    = tid >> 6;
    const int q    = lane & 31;      // this lane's q-row within the wave tile
    const int hi   = lane >> 5;      // kpos/dk-half selector
    const int bh   = blockIdx.y;
    const int q0   = blockIdx.x * 256 + w * 32;

    // ---- Q fragments (B-operand: col=q, k=dk chunk). 4 steps of dk=16. ----
    const u16* qp = Qb + ((size_t)bh * SEQ + q0 + q) * DK + hi * 8;
    bf16x8 qf0 = *(const bf16x8*)(qp);
    bf16x8 qf1 = *(const bf16x8*)(qp + 16);
    bf16x8 qf2 = *(const bf16x8*)(qp + 32);
    bf16x8 qf3 = *(const bf16x8*)(qp + 48);

    // ---- staging setup: waves 0-3 stage K[32][64], waves 4-7 stage V^T[64][40] ----
    const bool isK = tid < 256;
    const int t2   = isK ? tid : tid - 256;
    const int sr   = isK ? (t2 >> 3) : (t2 >> 2);   // row
    const int sc   = isK ? (t2 & 7) : (t2 & 3);     // 16B chunk
    const u16* gsrc = isK
        ? Kb  + ((size_t)bh * SEQ + sr) * DK + sc * 8
        : Vtb + ((size_t)bh * DK + sr) * SEQ + sc * 8;
    const int ldst = isK ? (sr * 64 + ((sc ^ (sr & 7)) * 8))            // K: XOR swizzle
                         : (4096 + sr * 40 + sc * 8);                    // V: padded rows
    const int lstep = isK ? 2048 : 2560;  // per-buffer stride (elems)
    const int gstep = isK ? 32 * DK : 32; // global stride per k-tile (elems)

    f32x16 oacc0 = {0.f}, oacc1 = {0.f};
#pragma unroll
    for (int r = 0; r < 16; r++) { oacc0[r] = 0.f; oacc1[r] = 0.f; }
    float m_ = -1e30f, l_ = 0.f;

    // prologue: stage tile 0 into buffer 0
    uint4 stg = *(const uint4*)gsrc;
    *(uint4*)&smem[ldst] = stg;
    __syncthreads();

    for (int t = 0; t < SEQ / 32; t++) {
        uint4 nstg;
        if (t < SEQ / 32 - 1) nstg = *(const uint4*)(gsrc + (size_t)(t + 1) * gstep);
        const int cur = t & 1;
        const u16* Kl = smem + cur * 2048;
        const u16* Vl = smem + 4096 + cur * 2560;

        // ---- S^T = K . Q^T ----
        f32x16 sacc = {0.f};
#pragma unroll
        for (int r = 0; r < 16; r++) sacc[r] = 0.f;
        {
            bf16x8 kf0 = *(const bf16x8*)&Kl[q * 64 + (((0 * 2 + hi) ^ (q & 7)) * 8)];
            bf16x8 kf1 = *(const bf16x8*)&Kl[q * 64 + (((1 * 2 + hi) ^ (q & 7)) * 8)];
            bf16x8 kf2 = *(const bf16x8*)&Kl[q * 64 + (((2 * 2 + hi) ^ (q & 7)) * 8)];
            bf16x8 kf3 = *(const bf16x8*)&Kl[q * 64 + (((3 * 2 + hi) ^ (q & 7)) * 8)];
            sacc = __builtin_amdgcn_mfma_f32_32x32x16_bf16(kf0, qf0, sacc, 0, 0, 0);
            sacc = __builtin_amdgcn_mfma_f32_32x32x16_bf16(kf1, qf1, sacc, 0, 0, 0);
            sacc = __builtin_amdgcn_mfma_f32_32x32x16_bf16(kf2, qf2, sacc, 0, 0, 0);
            sacc = __builtin_amdgcn_mfma_f32_32x32x16_bf16(kf3, qf3, sacc, 0, 0, 0);
        }

        // ---- in-register online softmax (scores already in log2 domain) ----
        float mx;
        {
            float a0 = fmaxf(sacc[0], sacc[1]),  a1 = fmaxf(sacc[2], sacc[3]);
            float a2 = fmaxf(sacc[4], sacc[5]),  a3 = fmaxf(sacc[6], sacc[7]);
            float a4 = fmaxf(sacc[8], sacc[9]),  a5 = fmaxf(sacc[10], sacc[11]);
            float a6 = fmaxf(sacc[12], sacc[13]), a7 = fmaxf(sacc[14], sacc[15]);
            a0 = fmaxf(a0, a1); a2 = fmaxf(a2, a3); a4 = fmaxf(a4, a5); a6 = fmaxf(a6, a7);
            mx = fmaxf(fmaxf(a0, a2), fmaxf(a4, a6));
        }
        mx = fmaxf(mx, __shfl_xor(mx, 32));
        // defer-max: only rescale when the running max grew by > 8 (=2^8 headroom)
        if (__any(mx > m_ + 8.f)) {
            float mnew = fmaxf(m_, mx);
            float sc_ = EXP2(m_ - mnew);
            m_ = mnew;
            l_ *= sc_;
            oacc0 *= sc_;
            oacc1 *= sc_;
        }
        float p[16];
#pragma unroll
        for (int r = 0; r < 16; r++) p[r] = EXP2(sacc[r] - m_);
        {
            float s0 = (p[0] + p[1]) + (p[2] + p[3]);
            float s1 = (p[4] + p[5]) + (p[6] + p[7]);
            float s2 = (p[8] + p[9]) + (p[10] + p[11]);
            float s3 = (p[12] + p[13]) + (p[14] + p[15]);
            float sm = (s0 + s1) + (s2 + s3);
            sm += __shfl_xor(sm, 32);
            l_ += sm;
        }

        // ---- pack P to bf16 + cross-half exchange -> P^T B-operand frags ----
        u32 w8[8], xw[8];
#pragma unroll
        for (int i = 0; i < 8; i++) w8[i] = pack2bf(p[2 * i], p[2 * i + 1]);
#pragma unroll
        for (int i = 0; i < 8; i++) xw[i] = __shfl_xor(w8[i], 32);
        union { u32 u[4]; bf16x8 v; } pf1, pf2;
        pf1.u[0] = hi ? xw[2] : w8[0];
        pf1.u[1] = hi ? xw[3] : w8[1];
        pf1.u[2] = hi ? w8[2] : xw[0];
        pf1.u[3] = hi ? w8[3] : xw[1];
        pf2.u[0] = hi ? xw[6] : w8[4];
        pf2.u[1] = hi ? xw[7] : w8[5];
        pf2.u[2] = hi ? w8[6] : xw[4];
        pf2.u[3] = hi ? w8[7] : xw[5];

        // ---- O^T += V^T . P^T ----
        {
            bf16x8 vf00 = *(const bf16x8*)&Vl[(q)      * 40 + 0 * 16 + hi * 8];
            bf16x8 vf01 = *(const bf16x8*)&Vl[(q)      * 40 + 1 * 16 + hi * 8];
            bf16x8 vf10 = *(const bf16x8*)&Vl[(q + 32) * 40 + 0 * 16 + hi * 8];
            bf16x8 vf11 = *(const bf16x8*)&Vl[(q + 32) * 40 + 1 * 16 + hi * 8];
            oacc0 = __builtin_amdgcn_mfma_f32_32x32x16_bf16(vf00, pf1.v, oacc0, 0, 0, 0);
            oacc0 = __builtin_amdgcn_mfma_f32_32x32x16_bf16(vf01, pf2.v, oacc0, 0, 0, 0);
            oacc1 = __builtin_amdgcn_mfma_f32_32x32x16_bf16(vf10, pf1.v, oacc1, 0, 0, 0);
            oacc1 = __builtin_amdgcn_mfma_f32_32x32x16_bf16(vf11, pf2.v, oacc1, 0, 0, 0);
        }

        // stage next tile into the other buffer, then sync
        if (t < SEQ / 32 - 1) *(uint4*)&smem[ldst + ((t + 1) & 1) * lstep] = nstg;
        __syncthreads();
    }

    // ---- epilogue: divide by l, bounce through LDS (swizzled) for coalesced store ----
    const float invl = 1.f / l_;
    const int wbase = w * 2048;
    __syncthreads();  // all waves done with K/V buffers
#pragma unroll
    for (int r = 0; r < 16; r++) {
        const int dk0 = 0 * 32 + (r & 3) + 8 * (r >> 2) + 4 * hi;
        const int dk1 = 1 * 32 + (r & 3) + 8 * (r >> 2) + 4 * hi;
        smem[wbase + q * 64 + (((dk0 >> 3) ^ (q & 7)) << 3) + (dk0 & 7)] = f2bf(oacc0[r] * invl);
        smem[wbase + q * 64 + (((dk1 >> 3) ^ (q & 7)) << 3) + (dk1 & 7)] = f2bf(oacc1[r] * invl);
    }
    __syncthreads();
    const int b = bh >> 4, h = bh & 15;
    const int r4 = lane >> 1;
    const int cc = (lane & 1) * 4;
#pragma unroll
    for (int c = 0; c < 4; c++) {
        const int chunk = cc + c;
        uint4 val = *(const uint4*)&smem[wbase + r4 * 64 + ((chunk ^ (r4 & 7)) << 3)];
        *(uint4*)&ctx[((size_t)(b * SEQ + q0 + r4)) * DMODEL + h * DK + chunk * 8] = val;
    }
}

// ---------------- in-place LayerNorm ----------------
__global__ __launch_bounds__(256) void ln_inplace(float* __restrict__ y,
                                                  const float* __restrict__ gamma,
                                                  const float* __restrict__ beta) {
    const int row = blockIdx.x;
    float* p = y + (size_t)row * DMODEL;
    const int tid = threadIdx.x;
    float4 v = *(const float4*)(p + tid * 4);
    float s  = v.x + v.y + v.z + v.w;
    float sq = v.x * v.x + v.y * v.y + v.z * v.z + v.w * v.w;
#pragma unroll
    for (int m = 1; m < 64; m <<= 1) {
        s  += __shfl_xor(s, m);
        sq += __shfl_xor(sq, m);
    }
    __shared__ float rs[4], rq[4];
    if ((tid & 63) == 0) { rs[tid >> 6] = s; rq[tid >> 6] = sq; }
    __syncthreads();
    s  = rs[0] + rs[1] + rs[2] + rs[3];
    sq = rq[0] + rq[1] + rq[2] + rq[3];
    const float mean = s * (1.0f / 1024.0f);
    const float var  = sq * (1.0f / 1024.0f) - mean * mean;
    const float inv  = rsqrtf(var + 1e-5f);
    const int c = tid * 4;
    float4 g4 = *(const float4*)(gamma + c);
    float4 b4 = *(const float4*)(beta + c);
    float4 o;
    o.x = (v.x - mean) * inv * g4.x + b4.x;
    o.y = (v.y - mean) * inv * g4.y + b4.y;
    o.z = (v.z - mean) * inv * g4.z + b4.z;
    o.w = (v.w - mean) * inv * g4.w + b4.w;
    *(float4*)(p + c) = o;
}

extern "C" void kernel_launch(void* const* d_in, const int* in_sizes, int n_in,
                              void* d_out, int out_size, void* d_ws, size_t ws_size,
                              hipStream_t stream) {
    const float* x     = (const float*)d_in[0];
    const float* Wq    = (const float*)d_in[1];
    const float* bq    = (const float*)d_in[2];
    const float* Wk    = (const float*)d_in[3];
    const float* bk    = (const float*)d_in[4];
    const float* Wv    = (const float*)d_in[5];
    const float* bv    = (const float*)d_in[6];
    const float* Wo    = (const float*)d_in[7];
    const float* bo    = (const float*)d_in[8];
    const float* gamma = (const float*)d_in[9];
    const float* beta  = (const float*)d_in[10];
    float* out = (float*)d_out;

    u16* x_bf    = (u16*)d_ws;
    u16* Wqkv_bf = x_bf + (size_t)NROWS * DMODEL;
    u16* Wo_bf   = Wqkv_bf + (size_t)3072 * 1024;
    u16* Q_bf    = Wo_bf + (size_t)1024 * 1024;
    u16* K_bf    = Q_bf + (size_t)64 * SEQ * DK;
    u16* Vt_bf   = K_bf + (size_t)64 * SEQ * DK;
    u16* ctx_bf  = x_bf;  // alias: x_bf dead after QKV GEMM

    cvt_f32_bf16<<<8192, 256, 0, stream>>>(x, x_bf, NROWS * DMODEL);
    cvt_f32_bf16<<<1024, 256, 0, stream>>>(Wq, Wqkv_bf, 1024 * 1024);
    cvt_f32_bf16<<<1024, 256, 0, stream>>>(Wk, Wqkv_bf + 1048576, 1024 * 1024);
    cvt_f32_bf16<<<1024, 256, 0, stream>>>(Wv, Wqkv_bf + 2097152, 1024 * 1024);
    cvt_f32_bf16<<<1024, 256, 0, stream>>>(Wo, Wo_bf, 1024 * 1024);

    gemm_bt<0><<<dim3(64, 24), 256, 0, stream>>>(x_bf, Wqkv_bf, 1024,
                                                 bq, bk, bv, Q_bf, K_bf, Vt_bf,
                                                 nullptr, nullptr);
    attn<<<dim3(8, 64), 512, 0, stream>>>(Q_bf, K_bf, Vt_bf, ctx_bf);
    gemm_bt<1><<<dim3(64, 8), 256, 0, stream>>>(ctx_bf, Wo_bf, 1024,
                                                bo, nullptr, nullptr,
                                                nullptr, nullptr, nullptr,
                                                x, out);
    ln_inplace<<<8192, 256, 0, stream>>>(out, gamma, beta);
}

// Round 3
// 235.684 us; speedup vs baseline: 2.0065x; 1.1038x over previous
//
#include <hip/hip_runtime.h>

// Fused MHA block: out = LayerNorm(x + MHA(x)).  B=4, S=2048, D=1024, H=16, dk=64.
// bf16 MFMA internal, fp32 I/O.
//
// Round 3:
//  GEMM: m97 structure — global_load_lds(16B) staging, BK=64, XOR-swizzled LDS
//        via pre-swizzled global source (linear LDS dest, rule #21).
//  attn: KVBLK=64, global_load_lds K/V staging (pre-swizzled source), 1 barrier
//        per tile, compiler cvt_pk bf16 packing, permlane32_swap P-exchange,
//        setprio around MFMA clusters, bh-major grid for per-XCD K/V L2 reuse.

#define SEQ 2048
#define DMODEL 1024
#define NH 16
#define DK 64
#define NROWS 8192  // B*S

typedef unsigned short u16;
typedef unsigned int u32;
typedef __bf16 bf16;
typedef bf16 bf16x8 __attribute__((ext_vector_type(8)));
typedef float f32x4 __attribute__((ext_vector_type(4)));
typedef float f32x16 __attribute__((ext_vector_type(16)));
typedef unsigned u32x2 __attribute__((ext_vector_type(2)));

#if __has_builtin(__builtin_amdgcn_exp2f)
#define EXP2(x) __builtin_amdgcn_exp2f(x)
#else
#define EXP2(x) __expf((x)*0.6931471805599453f)
#endif

// compiler-cast bf16 (emits v_cvt_pk_bf16_f32 for pairs; RNE)
__device__ inline u16 bfbits(float f) { return __builtin_bit_cast(u16, (bf16)f); }
__device__ inline u32 packbf2(float a, float b) {
    return (u32)bfbits(a) | ((u32)bfbits(b) << 16);
}

// async global->LDS, 16B per lane; LDS dest must be wave-uniform base (+lane*16)
__device__ inline void gload16(const u16* g, u16* l) {
    __builtin_amdgcn_global_load_lds(
        (const __attribute__((address_space(1))) u32*)g,
        (__attribute__((address_space(3))) u32*)l, 16, 0, 0);
}

// cross-half exchange: (a,b) -> (a with hi-lanes = b's lo-lanes, b with lo-lanes = a's hi-lanes)
__device__ inline void plswap(u32& a, u32& b) {
#if __has_builtin(__builtin_amdgcn_permlane32_swap)
    u32x2 r = __builtin_amdgcn_permlane32_swap(a, b, false, false);
    a = r[0]; b = r[1];
#else
    u32 xa = __shfl_xor(a, 32), xb = __shfl_xor(b, 32);
    int hi = (threadIdx.x & 63) >> 5;
    u32 na = hi ? xb : a;
    u32 nb = hi ? b : xa;
    a = na; b = nb;
#endif
}

// ---------------- fp32 -> bf16 convert ----------------
__global__ __launch_bounds__(256) void cvt_f32_bf16(const float* __restrict__ in,
                                                    u16* __restrict__ out, int n) {
    int i = (blockIdx.x * 256 + threadIdx.x) * 4;
    if (i >= n) return;
    float4 v = *(const float4*)(in + i);
    ushort4 o;
    o.x = bfbits(v.x); o.y = bfbits(v.y); o.z = bfbits(v.z); o.w = bfbits(v.w);
    *(ushort4*)(out + i) = o;
}

// ---------------- GEMM: C[M,N] = A[M,K=1024] @ W[N,K]^T (+epilogue) ----------------
// 128x128 tile, BK=64, 256 thr = 4 waves (2x2), wave = 64x64 = 4x4 16x16x32 frags.
// Staging: global_load_lds 16B, LDS linear [128][64], XOR swizzle (chunk ^= row&7)
// applied on the GLOBAL source and on the ds_read side (involution).
template <int EPI>
__global__ __launch_bounds__(256) void gemm_bt(
    const u16* __restrict__ A, const u16* __restrict__ Bm,
    const float* __restrict__ bias0, const float* __restrict__ bias1,
    const float* __restrict__ bias2,
    u16* __restrict__ Qo, u16* __restrict__ Ko, u16* __restrict__ Vo,
    const float* __restrict__ xres, float* __restrict__ yout) {
    __shared__ __align__(16) u16 As[128 * 64];
    __shared__ __align__(16) u16 Bs[128 * 64];

    const int tid  = threadIdx.x;
    const int lane = tid & 63;
    const int w    = tid >> 6;
    const int wr   = (w >> 1) * 64;
    const int wc   = (w & 1) * 64;
    const int l16  = lane & 15;
    const int lq   = lane >> 4;          // 0..3 (k-chunk)
    const int m0   = blockIdx.x * 128;
    const int n0   = blockIdx.y * 128;

    f32x4 acc[4][4];
#pragma unroll
    for (int m = 0; m < 4; m++)
#pragma unroll
        for (int n = 0; n < 4; n++) {
            f32x4 z = {0.f, 0.f, 0.f, 0.f};
            acc[m][n] = z;
        }

    // staging: wave w stages rows [w*32, w*32+32), 4 issues of 8 rows each.
    // lane l: row-in-8 = l>>3, source chunk = (l&7) ^ (l>>3)  (row&7 == l>>3)
    const int l8r = lane >> 3;
    const int sch = (lane & 7) ^ l8r;
    const u16* a_g = A  + (size_t)(m0 + w * 32 + l8r) * 1024 + sch * 8;
    const u16* b_g = Bm + (size_t)(n0 + w * 32 + l8r) * 1024 + sch * 8;

    for (int k0 = 0; k0 < 1024; k0 += 64) {
        __syncthreads();   // previous iteration's ds_reads done
#pragma unroll
        for (int i = 0; i < 4; i++) {
            gload16(a_g + (size_t)i * 8192 + k0, As + (w * 32 + i * 8) * 64);
            gload16(b_g + (size_t)i * 8192 + k0, Bs + (w * 32 + i * 8) * 64);
        }
        __syncthreads();   // drains vmcnt -> tile ready

#pragma unroll
        for (int kk = 0; kk < 2; kk++) {
            bf16x8 af[4], bfr[4];
#pragma unroll
            for (int m = 0; m < 4; m++)
                af[m] = *(const bf16x8*)&As[(wr + m * 16 + l16) * 64 +
                                            (((kk << 2) | lq) ^ (l16 & 7)) * 8];
#pragma unroll
            for (int n = 0; n < 4; n++)
                bfr[n] = *(const bf16x8*)&Bs[(wc + n * 16 + l16) * 64 +
                                             (((kk << 2) | lq) ^ (l16 & 7)) * 8];
            __builtin_amdgcn_s_setprio(1);
#pragma unroll
            for (int m = 0; m < 4; m++)
#pragma unroll
                for (int n = 0; n < 4; n++)
                    acc[m][n] = __builtin_amdgcn_mfma_f32_16x16x32_bf16(
                        af[m], bfr[n], acc[m][n], 0, 0, 0);
            __builtin_amdgcn_s_setprio(0);
        }
    }

    // epilogue. D-frag: col = lane&15, row = (lane>>4)*4 + r  [m89 verified]
    const int rbase = m0 + wr + lq * 4;
    const int cbase = n0 + wc + l16;
#pragma unroll
    for (int m = 0; m < 4; m++)
#pragma unroll
        for (int n = 0; n < 4; n++) {
            const int col = cbase + n * 16;
#pragma unroll
            for (int r = 0; r < 4; r++) {
                const int row = rbase + m * 16 + r;
                float v = acc[m][n][r];
                if (EPI == 0) {
                    const int which = col >> 10;
                    const int e = col & 1023;
                    const float* bs = (which == 0) ? bias0 : (which == 1) ? bias1 : bias2;
                    v += bs[e];
                    // fold 1/sqrt(dk) * log2(e) into Q (softmax in exp2 domain)
                    if (which == 0) v *= 0.18033688011112042f;
                    const int h = e >> 6, d = e & 63;
                    const int b = row >> 11, s = row & 2047;
                    const int bh = b * NH + h;
                    if (which == 2)
                        Vo[((size_t)bh * DK + d) * SEQ + s] = bfbits(v);
                    else if (which == 0)
                        Qo[((size_t)bh * SEQ + s) * DK + d] = bfbits(v);
                    else
                        Ko[((size_t)bh * SEQ + s) * DK + d] = bfbits(v);
                } else {
                    v += bias0[col] + xres[(size_t)row * DMODEL + col];
                    yout[(size_t)row * DMODEL + col] = v;
                }
            }
        }
}

// ---------------- flash attention, swapped-QK^T, KVBLK=64 ----------------
// grid (B*H, S/256), 512 thr = 8 waves; wave w owns q rows [q0, q0+32).
// K/V staged by global_load_lds (pre-swizzled source), double-buffered,
// ONE barrier per 64-kpos tile.
__global__ __launch_bounds__(512) void attn(const u16* __restrict__ Qb,
                                            const u16* __restrict__ Kb,
                                            const u16* __restrict__ Vtb,
                                            u16* __restrict__ ctx) {
    // carve: K bufs 2x[64][64] at elems 0..8191, V^T bufs 2x[64][64] at 8192..16383.
    // whole 16384 reused as output bounce (8 waves x 2048).
    __shared__ __align__(16) u16 smem[16384];

    const int tid  = threadIdx.x;
    const int lane = tid & 63;
    const int w    = tid >> 6;
    const int q    = lane & 31;
    const int hi   = lane >> 5;
    const int bh   = blockIdx.x;          // bh-major: q-blocks of one bh colocate per XCD
    const int q0   = blockIdx.y * 256 + w * 32;

    // Q fragments (B-operand: col=q, k=dk). qf[i] covers dk = i*16 + hi*8.
    const u16* qp = Qb + ((size_t)bh * SEQ + q0 + q) * DK + hi * 8;
    bf16x8 qf0 = *(const bf16x8*)(qp);
    bf16x8 qf1 = *(const bf16x8*)(qp + 16);
    bf16x8 qf2 = *(const bf16x8*)(qp + 32);
    bf16x8 qf3 = *(const bf16x8*)(qp + 48);

    // staging: wave w stages K rows [w*8, w*8+8) and V^T rows [w*8, w*8+8).
    // lane l: row-in-8 = l>>3, source chunk = (l&7)^(l>>3).
    const int l8r = lane >> 3;
    const int sch = (lane & 7) ^ l8r;
    const u16* kg = Kb  + ((size_t)bh * SEQ + w * 8 + l8r) * 64 + sch * 8;   // +4096/tile
    const u16* vg = Vtb + ((size_t)bh * DK  + w * 8 + l8r) * SEQ + sch * 8;  // +64/tile
    u16* kl = smem + w * 512;           // buffer stride 4096 elems
    u16* vl = smem + 8192 + w * 512;

    f32x16 oacc0, oacc1;
#pragma unroll
    for (int r = 0; r < 16; r++) { oacc0[r] = 0.f; oacc1[r] = 0.f; }
    float m_ = -1e30f, l_ = 0.f;

    // prologue: stage tile 0 into buffer 0
    gload16(kg, kl);
    gload16(vg, vl);
    __syncthreads();

    for (int t = 0; t < SEQ / 64; t++) {
        if (t < SEQ / 64 - 1) {
            gload16(kg + (size_t)(t + 1) * 4096, kl + ((t + 1) & 1) * 4096);
            gload16(vg + (size_t)(t + 1) * 64,  vl + ((t + 1) & 1) * 4096);
        }
        const u16* Kl = smem + (t & 1) * 4096;
        const u16* Vl = smem + 8192 + (t & 1) * 4096;

        // ---- S^T = K . Q^T : 2 kpos-tiles x 4 dk-steps ----
        f32x16 sacc0, sacc1;
#pragma unroll
        for (int r = 0; r < 16; r++) { sacc0[r] = 0.f; sacc1[r] = 0.f; }
        {
            // A-frag: row = kpos = kt*32 + q, chunk = ks*2+hi, swizzle ^ (q&7)
            bf16x8 k00 = *(const bf16x8*)&Kl[(q)      * 64 + (((0 << 1) | hi) ^ (q & 7)) * 8];
            bf16x8 k01 = *(const bf16x8*)&Kl[(q)      * 64 + (((1 << 1) | hi) ^ (q & 7)) * 8];
            bf16x8 k02 = *(const bf16x8*)&Kl[(q)      * 64 + (((2 << 1) | hi) ^ (q & 7)) * 8];
            bf16x8 k03 = *(const bf16x8*)&Kl[(q)      * 64 + (((3 << 1) | hi) ^ (q & 7)) * 8];
            bf16x8 k10 = *(const bf16x8*)&Kl[(q + 32) * 64 + (((0 << 1) | hi) ^ (q & 7)) * 8];
            bf16x8 k11 = *(const bf16x8*)&Kl[(q + 32) * 64 + (((1 << 1) | hi) ^ (q & 7)) * 8];
            bf16x8 k12 = *(const bf16x8*)&Kl[(q + 32) * 64 + (((2 << 1) | hi) ^ (q & 7)) * 8];
            bf16x8 k13 = *(const bf16x8*)&Kl[(q + 32) * 64 + (((3 << 1) | hi) ^ (q & 7)) * 8];
            __builtin_amdgcn_s_setprio(1);
            sacc0 = __builtin_amdgcn_mfma_f32_32x32x16_bf16(k00, qf0, sacc0, 0, 0, 0);
            sacc0 = __builtin_amdgcn_mfma_f32_32x32x16_bf16(k01, qf1, sacc0, 0, 0, 0);
            sacc0 = __builtin_amdgcn_mfma_f32_32x32x16_bf16(k02, qf2, sacc0, 0, 0, 0);
            sacc0 = __builtin_amdgcn_mfma_f32_32x32x16_bf16(k03, qf3, sacc0, 0, 0, 0);
            sacc1 = __builtin_amdgcn_mfma_f32_32x32x16_bf16(k10, qf0, sacc1, 0, 0, 0);
            sacc1 = __builtin_amdgcn_mfma_f32_32x32x16_bf16(k11, qf1, sacc1, 0, 0, 0);
            sacc1 = __builtin_amdgcn_mfma_f32_32x32x16_bf16(k12, qf2, sacc1, 0, 0, 0);
            sacc1 = __builtin_amdgcn_mfma_f32_32x32x16_bf16(k13, qf3, sacc1, 0, 0, 0);
            __builtin_amdgcn_s_setprio(0);
        }

        // ---- online softmax over 32 scores/lane (log2 domain) ----
        float mx;
        {
            float a0 = fmaxf(fmaxf(sacc0[0], sacc0[1]), fmaxf(sacc0[2], sacc0[3]));
            float a1 = fmaxf(fmaxf(sacc0[4], sacc0[5]), fmaxf(sacc0[6], sacc0[7]));
            float a2 = fmaxf(fmaxf(sacc0[8], sacc0[9]), fmaxf(sacc0[10], sacc0[11]));
            float a3 = fmaxf(fmaxf(sacc0[12], sacc0[13]), fmaxf(sacc0[14], sacc0[15]));
            float b0 = fmaxf(fmaxf(sacc1[0], sacc1[1]), fmaxf(sacc1[2], sacc1[3]));
            float b1 = fmaxf(fmaxf(sacc1[4], sacc1[5]), fmaxf(sacc1[6], sacc1[7]));
            float b2 = fmaxf(fmaxf(sacc1[8], sacc1[9]), fmaxf(sacc1[10], sacc1[11]));
            float b3 = fmaxf(fmaxf(sacc1[12], sacc1[13]), fmaxf(sacc1[14], sacc1[15]));
            mx = fmaxf(fmaxf(fmaxf(a0, a1), fmaxf(a2, a3)),
                       fmaxf(fmaxf(b0, b1), fmaxf(b2, b3)));
        }
        mx = fmaxf(mx, __shfl_xor(mx, 32));
        if (__any(mx > m_ + 8.f)) {       // defer-max, 2^8 headroom
            float mnew = fmaxf(m_, mx);
            float sc_ = EXP2(m_ - mnew);
            m_ = mnew;
            l_ *= sc_;
            oacc0 *= sc_;
            oacc1 *= sc_;
        }
#pragma unroll
        for (int r = 0; r < 16; r++) sacc0[r] = EXP2(sacc0[r] - m_);
#pragma unroll
        for (int r = 0; r < 16; r++) sacc1[r] = EXP2(sacc1[r] - m_);
        {
            float s0 = ((sacc0[0] + sacc0[1]) + (sacc0[2] + sacc0[3])) +
                       ((sacc0[4] + sacc0[5]) + (sacc0[6] + sacc0[7]));
            float s1 = ((sacc0[8] + sacc0[9]) + (sacc0[10] + sacc0[11])) +
                       ((sacc0[12] + sacc0[13]) + (sacc0[14] + sacc0[15]));
            float s2 = ((sacc1[0] + sacc1[1]) + (sacc1[2] + sacc1[3])) +
                       ((sacc1[4] + sacc1[5]) + (sacc1[6] + sacc1[7]));
            float s3 = ((sacc1[8] + sacc1[9]) + (sacc1[10] + sacc1[11])) +
                       ((sacc1[12] + sacc1[13]) + (sacc1[14] + sacc1[15]));
            float sm = (s0 + s1) + (s2 + s3);
            sm += __shfl_xor(sm, 32);
            l_ += sm;
        }

        // ---- pack P to bf16 + permlane exchange -> P^T B-frags ----
        u32 wa[8], wb[8];
#pragma unroll
        for (int i = 0; i < 8; i++) wa[i] = packbf2(sacc0[2 * i], sacc0[2 * i + 1]);
#pragma unroll
        for (int i = 0; i < 8; i++) wb[i] = packbf2(sacc1[2 * i], sacc1[2 * i + 1]);
        plswap(wa[0], wa[2]); plswap(wa[1], wa[3]);
        plswap(wa[4], wa[6]); plswap(wa[5], wa[7]);
        plswap(wb[0], wb[2]); plswap(wb[1], wb[3]);
        plswap(wb[4], wb[6]); plswap(wb[5], wb[7]);
        union { u32 u[4]; bf16x8 v; } pf0, pf1, pf2, pf3;
        pf0.u[0] = wa[0]; pf0.u[1] = wa[1]; pf0.u[2] = wa[2]; pf0.u[3] = wa[3];
        pf1.u[0] = wa[4]; pf1.u[1] = wa[5]; pf1.u[2] = wa[6]; pf1.u[3] = wa[7];
        pf2.u[0] = wb[0]; pf2.u[1] = wb[1]; pf2.u[2] = wb[2]; pf2.u[3] = wb[3];
        pf3.u[0] = wb[4]; pf3.u[1] = wb[5]; pf3.u[2] = wb[6]; pf3.u[3] = wb[7];

        // ---- O^T += V^T . P^T : 2 dk-halves x 4 kpos-steps ----
        {
            bf16x8 v00 = *(const bf16x8*)&Vl[(q)      * 64 + (((0 << 1) | hi) ^ (q & 7)) * 8];
            bf16x8 v01 = *(const bf16x8*)&Vl[(q)      * 64 + (((1 << 1) | hi) ^ (q & 7)) * 8];
            bf16x8 v02 = *(const bf16x8*)&Vl[(q)      * 64 + (((2 << 1) | hi) ^ (q & 7)) * 8];
            bf16x8 v03 = *(const bf16x8*)&Vl[(q)      * 64 + (((3 << 1) | hi) ^ (q & 7)) * 8];
            bf16x8 v10 = *(const bf16x8*)&Vl[(q + 32) * 64 + (((0 << 1) | hi) ^ (q & 7)) * 8];
            bf16x8 v11 = *(const bf16x8*)&Vl[(q + 32) * 64 + (((1 << 1) | hi) ^ (q & 7)) * 8];
            bf16x8 v12 = *(const bf16x8*)&Vl[(q + 32) * 64 + (((2 << 1) | hi) ^ (q & 7)) * 8];
            bf16x8 v13 = *(const bf16x8*)&Vl[(q + 32) * 64 + (((3 << 1) | hi) ^ (q & 7)) * 8];
            __builtin_amdgcn_s_setprio(1);
            oacc0 = __builtin_amdgcn_mfma_f32_32x32x16_bf16(v00, pf0.v, oacc0, 0, 0, 0);
            oacc0 = __builtin_amdgcn_mfma_f32_32x32x16_bf16(v01, pf1.v, oacc0, 0, 0, 0);
            oacc0 = __builtin_amdgcn_mfma_f32_32x32x16_bf16(v02, pf2.v, oacc0, 0, 0, 0);
            oacc0 = __builtin_amdgcn_mfma_f32_32x32x16_bf16(v03, pf3.v, oacc0, 0, 0, 0);
            oacc1 = __builtin_amdgcn_mfma_f32_32x32x16_bf16(v10, pf0.v, oacc1, 0, 0, 0);
            oacc1 = __builtin_amdgcn_mfma_f32_32x32x16_bf16(v11, pf1.v, oacc1, 0, 0, 0);
            oacc1 = __builtin_amdgcn_mfma_f32_32x32x16_bf16(v12, pf2.v, oacc1, 0, 0, 0);
            oacc1 = __builtin_amdgcn_mfma_f32_32x32x16_bf16(v13, pf3.v, oacc1, 0, 0, 0);
            __builtin_amdgcn_s_setprio(0);
        }

        __syncthreads();   // drains prefetch vmcnt; next tile ready, buffers safe
    }

    // ---- epilogue: /l, bounce through LDS (swizzled) for coalesced store ----
    const float invl = 1.f / l_;
    const int wbase = w * 2048;
#pragma unroll
    for (int r = 0; r < 16; r++) {
        const int dk0 = (r & 3) + 8 * (r >> 2) + 4 * hi;
        const int dk1 = 32 + dk0;
        smem[wbase + q * 64 + (((dk0 >> 3) ^ (q & 7)) << 3) + (dk0 & 7)] = bfbits(oacc0[r] * invl);
        smem[wbase + q * 64 + (((dk1 >> 3) ^ (q & 7)) << 3) + (dk1 & 7)] = bfbits(oacc1[r] * invl);
    }
    __syncthreads();
    const int b = bh >> 4, h = bh & 15;
    const int r4 = lane >> 1;
    const int cc = (lane & 1) * 4;
#pragma unroll
    for (int c = 0; c < 4; c++) {
        const int chunk = cc + c;
        uint4 val = *(const uint4*)&smem[wbase + r4 * 64 + ((chunk ^ (r4 & 7)) << 3)];
        *(uint4*)&ctx[((size_t)(b * SEQ + q0 + r4)) * DMODEL + h * DK + chunk * 8] = val;
    }
}

// ---------------- in-place LayerNorm ----------------
__global__ __launch_bounds__(256) void ln_inplace(float* __restrict__ y,
                                                  const float* __restrict__ gamma,
                                                  const float* __restrict__ beta) {
    const int row = blockIdx.x;
    float* p = y + (size_t)row * DMODEL;
    const int tid = threadIdx.x;
    float4 v = *(const float4*)(p + tid * 4);
    float s  = v.x + v.y + v.z + v.w;
    float sq = v.x * v.x + v.y * v.y + v.z * v.z + v.w * v.w;
#pragma unroll
    for (int m = 1; m < 64; m <<= 1) {
        s  += __shfl_xor(s, m);
        sq += __shfl_xor(sq, m);
    }
    __shared__ float rs[4], rq[4];
    if ((tid & 63) == 0) { rs[tid >> 6] = s; rq[tid >> 6] = sq; }
    __syncthreads();
    s  = rs[0] + rs[1] + rs[2] + rs[3];
    sq = rq[0] + rq[1] + rq[2] + rq[3];
    const float mean = s * (1.0f / 1024.0f);
    const float var  = sq * (1.0f / 1024.0f) - mean * mean;
    const float inv  = rsqrtf(var + 1e-5f);
    const int c = tid * 4;
    float4 g4 = *(const float4*)(gamma + c);
    float4 b4 = *(const float4*)(beta + c);
    float4 o;
    o.x = (v.x - mean) * inv * g4.x + b4.x;
    o.y = (v.y - mean) * inv * g4.y + b4.y;
    o.z = (v.z - mean) * inv * g4.z + b4.z;
    o.w = (v.w - mean) * inv * g4.w + b4.w;
    *(float4*)(p + c) = o;
}

extern "C" void kernel_launch(void* const* d_in, const int* in_sizes, int n_in,
                              void* d_out, int out_size, void* d_ws, size_t ws_size,
                              hipStream_t stream) {
    const float* x     = (const float*)d_in[0];
    const float* Wq    = (const float*)d_in[1];
    const float* bq    = (const float*)d_in[2];
    const float* Wk    = (const float*)d_in[3];
    const float* bk    = (const float*)d_in[4];
    const float* Wv    = (const float*)d_in[5];
    const float* bv    = (const float*)d_in[6];
    const float* Wo    = (const float*)d_in[7];
    const float* bo    = (const float*)d_in[8];
    const float* gamma = (const float*)d_in[9];
    const float* beta  = (const float*)d_in[10];
    float* out = (float*)d_out;

    u16* x_bf    = (u16*)d_ws;
    u16* Wqkv_bf = x_bf + (size_t)NROWS * DMODEL;
    u16* Wo_bf   = Wqkv_bf + (size_t)3072 * 1024;
    u16* Q_bf    = Wo_bf + (size_t)1024 * 1024;
    u16* K_bf    = Q_bf + (size_t)64 * SEQ * DK;
    u16* Vt_bf   = K_bf + (size_t)64 * SEQ * DK;
    u16* ctx_bf  = x_bf;  // alias: x_bf dead after QKV GEMM

    cvt_f32_bf16<<<8192, 256, 0, stream>>>(x, x_bf, NROWS * DMODEL);
    cvt_f32_bf16<<<1024, 256, 0, stream>>>(Wq, Wqkv_bf, 1024 * 1024);
    cvt_f32_bf16<<<1024, 256, 0, stream>>>(Wk, Wqkv_bf + 1048576, 1024 * 1024);
    cvt_f32_bf16<<<1024, 256, 0, stream>>>(Wv, Wqkv_bf + 2097152, 1024 * 1024);
    cvt_f32_bf16<<<1024, 256, 0, stream>>>(Wo, Wo_bf, 1024 * 1024);

    gemm_bt<0><<<dim3(64, 24), 256, 0, stream>>>(x_bf, Wqkv_bf,
                                                 bq, bk, bv, Q_bf, K_bf, Vt_bf,
                                                 nullptr, nullptr);
    attn<<<dim3(64, 8), 512, 0, stream>>>(Q_bf, K_bf, Vt_bf, ctx_bf);
    gemm_bt<1><<<dim3(64, 8), 256, 0, stream>>>(ctx_bf, Wo_bf,
                                                bo, nullptr, nullptr,
                                                nullptr, nullptr, nullptr,
                                                x, out);
    ln_inplace<<<8192, 256, 0, stream>>>(out, gamma, beta);
}